// Round 1
// 346.102 us; speedup vs baseline: 1.0360x; 1.0360x over previous
//
#include <hip/hip_runtime.h>

// FragAttention: masked prefix-sum along s.
//   x: (S, B, D) f32, src_mask: (B, S) int (True=pad)
//   out: (B, G, 2D) f32, G = S-1
//   left[b,g,d]  = sum_{s<=g} x[s,b,d]*valid[b,s]
//   right[b,g,d] = total[b,d] - left[b,g,d]
//
// R1 changes vs 359us baseline:
//  - CS 16->8: v[] drops 64->32 VGPRs; ~70 total with accumulators ->
//    __launch_bounds__(512,6) caps at 84 VGPR, 3 blocks (24 waves)/CU
//    instead of 2 blocks (16 waves)/CU.
//  - nontemporal load/store on the two pure streams (x read once, out
//    written once; out alone ~= the whole 256MB L3 -> don't allocate).
//  - geometry: block = 512 thr = 16 s-chunks x 32 float4-cols (128 d's),
//    grid = 4 blocks per b = 2048. Wave = 2 chunks x 32 cols -> every
//    global instr touches two 512B fully-covered segments.
#define SS 128
#define BB 512
#define DD 512
#define GG 127
#define CS 8     // s-values per thread
#define NC 16    // chunks
#define NCOL 32  // float4 columns per block (= 128 floats of d)

typedef float f4 __attribute__((ext_vector_type(4)));

__global__ __launch_bounds__(512, 6) void frag_prefix_kernel(
    const float* __restrict__ x, const int* __restrict__ mask,
    float* __restrict__ out) {
  const int tid = threadIdx.x;
  const int b = blockIdx.x >> 2;
  const int dblk = (blockIdx.x & 3) << 7;  // 0,128,256,384 (floats)
  const int col = tid & (NCOL - 1);        // float4 column within block
  const int j = tid >> 5;                  // s-chunk id, 0..15

  __shared__ float valid[SS];
  __shared__ f4 part[NC][NCOL];

  if (tid < SS) valid[tid] = mask[b * SS + tid] ? 0.0f : 1.0f;
  __syncthreads();

  // x as f4: s-stride = B*D/4 f4's.
  const size_t sstride = (size_t)BB * DD / 4;
  const f4* xq = (const f4*)x + (size_t)(j * CS) * sstride +
                 ((size_t)b * DD + dblk) / 4 + col;

  f4 v[CS];
#pragma unroll
  for (int i = 0; i < CS; ++i) {
    f4 t = __builtin_nontemporal_load(xq + (size_t)i * sstride);
    v[i] = t * valid[j * CS + i];
  }

  f4 psum = v[0];
#pragma unroll
  for (int i = 1; i < CS; ++i) psum += v[i];
  part[j][col] = psum;
  __syncthreads();

  f4 offset = {0.f, 0.f, 0.f, 0.f};
  f4 total = {0.f, 0.f, 0.f, 0.f};
#pragma unroll
  for (int jj = 0; jj < NC; ++jj) {
    f4 p = part[jj][col];
    total += p;
    if (jj < j) offset += p;
  }

  // out[b, g, c]: g-stride = 2*D/4 = 256 f4's; right half at +D/4 = +128.
  f4* op = (f4*)out + ((size_t)b * GG * 2 * DD + dblk) / 4 + col;
  f4 run = offset;
#pragma unroll
  for (int i = 0; i < CS; ++i) {
    run += v[i];
    const int g = j * CS + i;
    if (g < GG) {  // only chunk 15's last iteration skips
      __builtin_nontemporal_store(run, op + (size_t)g * (2 * DD / 4));
      f4 r = total - run;
      __builtin_nontemporal_store(r, op + (size_t)g * (2 * DD / 4) + DD / 4);
    }
  }
}

extern "C" void kernel_launch(void* const* d_in, const int* in_sizes, int n_in,
                              void* d_out, int out_size, void* d_ws, size_t ws_size,
                              hipStream_t stream) {
  const float* x = (const float*)d_in[0];
  const int* mask = (const int*)d_in[1];
  float* out = (float*)d_out;
  // 4 blocks per b (128 floats of d each) -> 2048 blocks x 512 threads.
  frag_prefix_kernel<<<dim3(BB * 4), dim3(512), 0, stream>>>(x, mask, out);
}